// Round 4
// baseline (952.171 us; speedup 1.0000x reference)
//
#include <hip/hip_runtime.h>
#include <stdint.h>

// Problem constants (MambaBlock: B=8, C=d=1024, H*W=L=1024, depth=4, S=128)
#define DT_STEP 0.001f
#define LN_EPS  1e-5f
#define Bn      8
#define Lseq    1024
#define Dm      1024
#define Sn      128
#define DEPTH   4
#define Mrows   (Bn * Lseq)       // 8192
#define Qc      32                // scan chunk size
#define NCHUNK  (Lseq / Qc)       // 32
#define NPOW    33                // powers 0..32 per layer

typedef short bf16x8 __attribute__((ext_vector_type(8)));
typedef float f32x4  __attribute__((ext_vector_type(4)));

__device__ __forceinline__ unsigned short f2bf(float f) {
    unsigned int u = __float_as_uint(f);
    u += 0x7fffu + ((u >> 16) & 1u);          // round-to-nearest-even
    return (unsigned short)(u >> 16);
}

// async 16B global->LDS (wave-uniform base + lane*16; slot index linear in lane)
#define GLOAD_LDS16(gp, lp)                                                \
    __builtin_amdgcn_global_load_lds(                                      \
        (const __attribute__((address_space(1))) unsigned int*)(gp),       \
        (__attribute__((address_space(3))) unsigned int*)(lp), 16, 0, 0)

// ---------------------------------------------------------------------------
// fp32 -> bf16 elementwise convert (n multiple of 1024)
// ---------------------------------------------------------------------------
__global__ __launch_bounds__(256) void f2bf_kernel(const float* __restrict__ src,
                                                   unsigned short* __restrict__ dst,
                                                   int n) {
    int i = (blockIdx.x * 256 + threadIdx.x) * 4;
    if (i < n) {
        float4 v = *(const float4*)(src + i);
        ushort4 o;
        o.x = f2bf(v.x); o.y = f2bf(v.y); o.z = f2bf(v.z); o.w = f2bf(v.w);
        *(ushort4*)(dst + i) = o;
    }
}

// Wo2[j,k] = bf16(Wo[j,k] * Dp[k])  (per-layer z)
__global__ __launch_bounds__(256) void convscale_kernel(const float* __restrict__ Wo,
                                                        const float* __restrict__ Dp,
                                                        unsigned short* __restrict__ dst) {
    int z = blockIdx.y;
    int i = (blockIdx.x * 256 + threadIdx.x) * 4;
    const float* S = Wo + (size_t)z * Dm * Dm;
    const float* dp = Dp + (size_t)z * Dm;
    float4 v = *(const float4*)(S + i);
    int c = i & (Dm - 1);
    float4 d = *(const float4*)(dp + c);
    ushort4 o;
    o.x = f2bf(v.x * d.x); o.y = f2bf(v.y * d.y);
    o.z = f2bf(v.z * d.z); o.w = f2bf(v.w * d.w);
    *(ushort4*)(dst + (size_t)z * Dm * Dm + i) = o;
}

// transpose+convert: src (R x C) fp32 -> dst (C x R) bf16, batched z
__global__ __launch_bounds__(256) void transpose_f2bf(const float* __restrict__ src,
                                                      unsigned short* __restrict__ dst,
                                                      int R, int C) {
    __shared__ float t[32][33];
    int z = blockIdx.z;
    const float* S = src + (size_t)z * R * C;
    unsigned short* D = dst + (size_t)z * R * C;
    int r0 = blockIdx.y * 32, c0 = blockIdx.x * 32;
    int tx = threadIdx.x & 31, ty = threadIdx.x >> 5;   // 32 x 8
    for (int rr = ty; rr < 32; rr += 8)
        t[rr][tx] = S[(size_t)(r0 + rr) * C + c0 + tx];
    __syncthreads();
    for (int rr = ty; rr < 32; rr += 8)
        D[(size_t)(c0 + rr) * R + r0 + tx] = f2bf(t[tx][rr]);
}

// c2dt[z*Sn+s] = DT * sum_j Bp[z,s,j]*bi[z,j]
__global__ __launch_bounds__(256) void c2dt_kernel(const float* __restrict__ Bp,
                                                   const float* __restrict__ bi,
                                                   float* __restrict__ c2dt) {
    int z = blockIdx.x, s = blockIdx.y;
    int tid = threadIdx.x;
    const float* br = Bp + ((size_t)z * Sn + s) * Dm;
    const float* bb = bi + (size_t)z * Dm;
    float4 v = *(const float4*)(br + tid * 4);
    float4 w = *(const float4*)(bb + tid * 4);
    float acc = v.x * w.x + v.y * w.y + v.z * w.z + v.w * w.w;
#pragma unroll
    for (int off = 32; off > 0; off >>= 1) acc += __shfl_down(acc, off, 64);
    __shared__ float red[4];
    if ((tid & 63) == 0) red[tid >> 6] = acc;
    __syncthreads();
    if (tid == 0) c2dt[z * Sn + s] = DT_STEP * (red[0] + red[1] + red[2] + red[3]);
}

// ---------------------------------------------------------------------------
// Batched 1024x1024 transpose fp32: dst[b][i][j] = src[b][j][i]
// ---------------------------------------------------------------------------
__global__ __launch_bounds__(1024) void transpose_bll(const float* __restrict__ src,
                                                      float* __restrict__ dst) {
    __shared__ float tile[32][33];
    int b  = blockIdx.z;
    int i0 = blockIdx.y * 32, j0 = blockIdx.x * 32;
    int tx = threadIdx.x, ty = threadIdx.y;
    const float* S = src + (size_t)b * Dm * Lseq;
    float*       D = dst + (size_t)b * Dm * Lseq;
    tile[ty][tx] = S[(size_t)(j0 + ty) * 1024 + i0 + tx];
    __syncthreads();
    D[(size_t)(i0 + ty) * 1024 + j0 + tx] = tile[tx][ty];
}

// ---------------------------------------------------------------------------
// Row LayerNorm, bf16 output
// ---------------------------------------------------------------------------
__global__ __launch_bounds__(256) void ln_kernel(const float* __restrict__ x,
                                                 unsigned short* __restrict__ outp,
                                                 const float* __restrict__ g,
                                                 const float* __restrict__ bta) {
    int row = blockIdx.x;
    int tid = threadIdx.x;
    const float* xr = x + (size_t)row * Dm;
    float4 v = *(const float4*)(xr + tid * 4);
    float s  = v.x + v.y + v.z + v.w;
    float ss = v.x * v.x + v.y * v.y + v.z * v.z + v.w * v.w;
#pragma unroll
    for (int off = 32; off > 0; off >>= 1) {
        s  += __shfl_down(s, off, 64);
        ss += __shfl_down(ss, off, 64);
    }
    __shared__ float red[8];
    __shared__ float mv[2];
    int wave = tid >> 6, lane = tid & 63;
    if (lane == 0) { red[wave] = s; red[4 + wave] = ss; }
    __syncthreads();
    if (tid == 0) {
        float st  = red[0] + red[1] + red[2] + red[3];
        float sst = red[4] + red[5] + red[6] + red[7];
        float mean = st / (float)Dm;
        float var  = sst / (float)Dm - mean * mean;
        mv[0] = mean;
        mv[1] = rsqrtf(var + LN_EPS);
    }
    __syncthreads();
    float mean = mv[0], rstd = mv[1];
    int c = tid * 4;
    float4 gv = *(const float4*)(g + c);
    float4 bv = *(const float4*)(bta + c);
    ushort4 o;
    o.x = f2bf((v.x - mean) * rstd * gv.x + bv.x);
    o.y = f2bf((v.y - mean) * rstd * gv.y + bv.y);
    o.z = f2bf((v.z - mean) * rstd * gv.z + bv.z);
    o.w = f2bf((v.w - mean) * rstd * gv.w + bv.w);
    *(ushort4*)(outp + (size_t)row * Dm + c) = o;
}

// ---------------------------------------------------------------------------
// NT GEMM, BK=64, bf16 MFMA, XOR-swizzled LDS, global_load_lds staging,
// EXPLICIT DOUBLE BUFFER with raw s_waitcnt vmcnt(8)/s_barrier (never drains
// the load queue to zero inside the K-loop -- AITER-style pipeline; the
// compiler's __syncthreads would force vmcnt(0) and stall all waves).
// Grid: 1-D flat, row_blk = flat % ny, col_blk = flat / ny  (XCD A-reuse).
// modes: see R3 comments (0: fused u+ub, 1: fused-K output+residual, 2: precompute)
// ---------------------------------------------------------------------------
__global__ __launch_bounds__(256) void gemm_bk64(
    const unsigned short* __restrict__ A1, int sA1,
    const unsigned short* __restrict__ A2, int sA2, int KA1,
    const unsigned short* __restrict__ B1, int sB1,
    const unsigned short* __restrict__ B2, int sB2,
    float* __restrict__ Cf, unsigned short* __restrict__ Ch,
    const float* __restrict__ bias1, const float* __restrict__ bias2,
    int ny, int N, int K, float scale, int mode,
    long batchA, long batchB, long batchC) {
    __shared__ __align__(16) unsigned short As[2][1024 * 8]; // 2 x 16 KB
    __shared__ __align__(16) unsigned short Bs[2][1024 * 8];
    int flat = blockIdx.x;
    int rb = flat % ny, cb = flat / ny;
    int row0 = rb * 128, col0 = cb * 128;
    int z = blockIdx.y;
    int tid  = threadIdx.x;
    int wave = tid >> 6, lane = tid & 63;
    int wm = (wave >> 1) * 64, wn = (wave & 1) * 64;
    int lr = lane & 15, lq = lane >> 4;

    // staging slots: s = tid + q*256; row = s>>3, phys kchunk = s&7,
    // logical kchunk = (s&7) ^ (row&7)
    int rowS[4], kclS[4], slotOff[4];
#pragma unroll
    for (int q = 0; q < 4; q++) {
        int s = tid + q * 256;
        rowS[q] = s >> 3;
        kclS[q] = (s & 7) ^ ((s >> 3) & 7);
        slotOff[q] = s * 8;
    }
    // fragment LDS offsets (shorts): slot = row*8 + ((lq+4h) ^ (row&7))
    int aoff[4][2], boff[4][2];
#pragma unroll
    for (int i = 0; i < 4; i++)
#pragma unroll
        for (int h = 0; h < 2; h++) {
            int ra = wm + i * 16 + lr;
            aoff[i][h] = (ra * 8 + ((lq + 4 * h) ^ (ra & 7))) * 8;
            int rn = wn + i * 16 + lr;
            boff[i][h] = (rn * 8 + ((lq + 4 * h) ^ (rn & 7))) * 8;
        }

    // pre-resolve fixed operands
    const unsigned short* A1b = A1 + (size_t)z * batchA;
    const unsigned short* BfixBlk = nullptr;
    int sBfix = sB1;
    if (mode == 0) {
        if (col0 < N - 128) { BfixBlk = B1 + (size_t)col0 * sB1; sBfix = sB1; }
        else                { BfixBlk = B2;                      sBfix = sB2; }
    } else if (mode == 2) {
        BfixBlk = B1 + (size_t)z * batchB + (size_t)col0 * sB1;
        sBfix = sB1;
    }

    // operand resolve + issue for K-iteration kt into buffer buf
    auto issue = [&](int kt, int buf) {
        int k0 = kt * 64;
        const unsigned short *Ab, *Bb;
        int sa, sb, ko;
        if (mode == 1) {
            if (k0 < KA1) { Ab = A1; sa = sA1; Bb = B1 + (size_t)col0 * sB1; sb = sB1; ko = k0; }
            else          { Ab = A2; sa = sA2; Bb = B2 + (size_t)col0 * sB2; sb = sB2; ko = k0 - KA1; }
        } else {
            Ab = A1b; sa = sA1; Bb = BfixBlk; sb = sBfix; ko = k0;
        }
        const unsigned short* Abr = Ab + (size_t)row0 * sa + ko;
        const unsigned short* Bbr = Bb + ko;
#pragma unroll
        for (int q = 0; q < 4; q++) {
            GLOAD_LDS16(Abr + (size_t)rowS[q] * sa + kclS[q] * 8, &As[buf][slotOff[q]]);
            GLOAD_LDS16(Bbr + (size_t)rowS[q] * sb + kclS[q] * 8, &Bs[buf][slotOff[q]]);
        }
    };

    f32x4 acc[4][4];
#pragma unroll
    for (int i = 0; i < 4; i++)
#pragma unroll
        for (int j = 0; j < 4; j++) acc[i][j] = (f32x4){0.f, 0.f, 0.f, 0.f};

    auto compute = [&](int buf) {
#pragma unroll
        for (int h = 0; h < 2; h++) {
            bf16x8 af[4], bfr[4];
#pragma unroll
            for (int i = 0; i < 4; i++) af[i]  = *(const bf16x8*)&As[buf][aoff[i][h]];
#pragma unroll
            for (int j = 0; j < 4; j++) bfr[j] = *(const bf16x8*)&Bs[buf][boff[j][h]];
#pragma unroll
            for (int i = 0; i < 4; i++)
#pragma unroll
                for (int j = 0; j < 4; j++)
                    acc[i][j] = __builtin_amdgcn_mfma_f32_16x16x32_bf16(af[i], bfr[j],
                                                                       acc[i][j], 0, 0, 0);
        }
    };

    int niter = K >> 6;
    issue(0, 0);
    int it = 0;
    for (; it + 1 < niter; it++) {
        issue(it + 1, (it + 1) & 1);
        // wait for the PREVIOUS tile's 8 loads only (8 newest stay in flight)
        asm volatile("s_waitcnt vmcnt(8)\n\ts_barrier" ::: "memory");
        compute(it & 1);
        // all waves done reading this buffer before it is refilled next iter
        asm volatile("s_waitcnt lgkmcnt(0)\n\ts_barrier" ::: "memory");
    }
    asm volatile("s_waitcnt vmcnt(0)\n\ts_barrier" ::: "memory");
    compute(it & 1);

    // Epilogue. C/D layout: row = lq*4 + r, col = lr (m89-verified)
#pragma unroll
    for (int i = 0; i < 4; i++) {
#pragma unroll
        for (int j = 0; j < 4; j++) {
#pragma unroll
            for (int r = 0; r < 4; r++) {
                int row = row0 + wm + i * 16 + lq * 4 + r;
                int col = col0 + wn + j * 16 + lr;
                float v = acc[i][j][r];
                if (mode == 0) {
                    int nu = N - 128;
                    if (col < nu) {
                        Ch[(size_t)row * nu + col] = f2bf(v + bias1[col]);
                    } else {
                        int cc = col - nu;
                        Cf[(size_t)row * 128 + cc] = v + bias2[cc];
                    }
                } else if (mode == 1) {
                    size_t idx = (size_t)row * N + col;
                    Cf[idx] = Cf[idx] + v + bias1[col];
                } else {
                    Ch[(size_t)z * batchC + (size_t)row * N + col] = f2bf(v * scale);
                }
            }
        }
    }
}

// ---------------------------------------------------------------------------
// Matrix powers of A_bar = I + DT*A (fp32 — bf16 would erase the DT*A part!)
// ---------------------------------------------------------------------------
__global__ __launch_bounds__(128) void pow_init(const float* __restrict__ Amat,
                                                float* __restrict__ Pow) {
    int i = blockIdx.x;   // layer
    int s = blockIdx.y;   // row
    int k = threadIdx.x;  // col
    float eye = (s == k) ? 1.f : 0.f;
    size_t base = (size_t)i * NPOW * (Sn * Sn);
    Pow[base + (size_t)s * Sn + k] = eye;  // A^0 = I
    Pow[base + (size_t)(Sn * Sn) + (size_t)s * Sn + k] =
        eye + DT_STEP * Amat[(size_t)i * Sn * Sn + (size_t)s * Sn + k];
}

// Pc = Pa @ Pb, each 128x128 fp32. Block computes 64x32 quadrant.
__global__ __launch_bounds__(256) void pow_mul(float* __restrict__ Pow, int m, int kmax) {
    int job = blockIdx.z;
    int i  = job / kmax;
    int kk = job % kmax + 1;
    const float* Pa = Pow + ((size_t)i * NPOW + m) * (Sn * Sn);
    const float* Pb = Pow + ((size_t)i * NPOW + kk) * (Sn * Sn);
    float*       Pc = Pow + ((size_t)i * NPOW + m + kk) * (Sn * Sn);
    int r0 = blockIdx.y * 64, c0 = blockIdx.x * 32;
    __shared__ float Asl[64 * 129];
    __shared__ float Bsl[128 * 32];
    int tx = threadIdx.x, ty = threadIdx.y;
    int tid = ty * 16 + tx;
    for (int idx = tid; idx < 64 * 128; idx += 256) {
        int r = idx >> 7, cc = idx & 127;
        Asl[r * 129 + cc] = Pa[(size_t)(r0 + r) * 128 + cc];
    }
    for (int idx = tid; idx < 128 * 32; idx += 256) {
        int r = idx >> 5, cc = idx & 31;
        Bsl[r * 32 + cc] = Pb[(size_t)r * 128 + c0 + cc];
    }
    __syncthreads();
    float acc[4][2] = {{0.f,0.f},{0.f,0.f},{0.f,0.f},{0.f,0.f}};
    for (int k = 0; k < 128; k++) {
        float b0 = Bsl[k * 32 + tx * 2];
        float b1 = Bsl[k * 32 + tx * 2 + 1];
#pragma unroll
        for (int r = 0; r < 4; r++) {
            float a = Asl[(ty * 4 + r) * 129 + k];
            acc[r][0] += a * b0;
            acc[r][1] += a * b1;
        }
    }
#pragma unroll
    for (int r = 0; r < 4; r++) {
        Pc[(size_t)(r0 + ty * 4 + r) * 128 + c0 + tx * 2]     = acc[r][0];
        Pc[(size_t)(r0 + ty * 4 + r) * 128 + c0 + tx * 2 + 1] = acc[r][1];
    }
}

// ---------------------------------------------------------------------------
// Chunk-local scan: per (b, chunk) block, h_t = A_bar@h_{t-1} + ub_t from h=0
// ---------------------------------------------------------------------------
__global__ __launch_bounds__(128) void local_scan(const float* __restrict__ ub,
                                                  float* __restrict__ hs,
                                                  const float* __restrict__ Abar) {
    int b = blockIdx.x / NCHUNK;
    int c = blockIdx.x % NCHUNK;
    int s = threadIdx.x;
    float arow[Sn];
#pragma unroll
    for (int k = 0; k < Sn; k += 4) {
        float4 v = *(const float4*)(Abar + (size_t)s * Sn + k);
        arow[k] = v.x; arow[k + 1] = v.y; arow[k + 2] = v.z; arow[k + 3] = v.w;
    }
    __shared__ __align__(16) float hsh[Sn];
    hsh[s] = 0.f;
    __syncthreads();
    size_t base = (size_t)(b * Lseq + c * Qc) * Sn + s;
    for (int t = 0; t < Qc; t++) {
        float ut = ub[base + (size_t)t * Sn];
        float a0 = 0.f, a1 = 0.f, a2 = 0.f, a3 = 0.f;
#pragma unroll
        for (int k = 0; k < Sn; k += 16) {
            float4 h0 = *(const float4*)&hsh[k];
            float4 h1 = *(const float4*)&hsh[k + 4];
            float4 h2 = *(const float4*)&hsh[k + 8];
            float4 h3 = *(const float4*)&hsh[k + 12];
            a0 += arow[k + 0] * h0.x + arow[k + 1] * h0.y + arow[k + 2] * h0.z + arow[k + 3] * h0.w;
            a1 += arow[k + 4] * h1.x + arow[k + 5] * h1.y + arow[k + 6] * h1.z + arow[k + 7] * h1.w;
            a2 += arow[k + 8] * h2.x + arow[k + 9] * h2.y + arow[k + 10] * h2.z + arow[k + 11] * h2.w;
            a3 += arow[k + 12] * h3.x + arow[k + 13] * h3.y + arow[k + 14] * h3.z + arow[k + 15] * h3.w;
        }
        float hv = ut + (a0 + a1) + (a2 + a3);
        hs[base + (size_t)t * Sn] = hv;
        __syncthreads();
        hsh[s] = hv;
        __syncthreads();
    }
}

// ---------------------------------------------------------------------------
// Cross-chunk carry scan with up-front prefetch of all chunk-end states.
// ---------------------------------------------------------------------------
__global__ __launch_bounds__(128) void carry_scan(const float* __restrict__ hs,
                                                  const float* __restrict__ AQ,
                                                  float* __restrict__ carry) {
    int b = blockIdx.x;
    int s = threadIdx.x;
    float le[NCHUNK];
#pragma unroll
    for (int c = 0; c < NCHUNK; c++)
        le[c] = hs[(size_t)(b * Lseq + c * Qc + Qc - 1) * Sn + s];
    float arow[Sn];
#pragma unroll
    for (int k = 0; k < Sn; k += 4) {
        float4 v = *(const float4*)(AQ + (size_t)s * Sn + k);
        arow[k] = v.x; arow[k + 1] = v.y; arow[k + 2] = v.z; arow[k + 3] = v.w;
    }
    __shared__ __align__(16) float csh[Sn];
    csh[s] = 0.f;
    __syncthreads();
    for (int c = 0; c < NCHUNK; c++) {
        carry[((size_t)b * NCHUNK + c) * Sn + s] = csh[s];
        float a0 = 0.f, a1 = 0.f, a2 = 0.f, a3 = 0.f;
#pragma unroll
        for (int k = 0; k < Sn; k += 16) {
            float4 h0 = *(const float4*)&csh[k];
            float4 h1 = *(const float4*)&csh[k + 4];
            float4 h2 = *(const float4*)&csh[k + 8];
            float4 h3 = *(const float4*)&csh[k + 12];
            a0 += arow[k + 0] * h0.x + arow[k + 1] * h0.y + arow[k + 2] * h0.z + arow[k + 3] * h0.w;
            a1 += arow[k + 4] * h1.x + arow[k + 5] * h1.y + arow[k + 6] * h1.z + arow[k + 7] * h1.w;
            a2 += arow[k + 8] * h2.x + arow[k + 9] * h2.y + arow[k + 10] * h2.z + arow[k + 11] * h2.w;
            a3 += arow[k + 12] * h3.x + arow[k + 13] * h3.y + arow[k + 14] * h3.z + arow[k + 15] * h3.w;
        }
        float cv = le[c] + (a0 + a1) + (a2 + a3);
        __syncthreads();
        csh[s] = cv;
        __syncthreads();
    }
}

// ---------------------------------------------------------------------------
// Fixup: hs_bf[b, c*Q+t, :] = bf16( hs[b,c*Q+t,:] + A^(t+1) @ carry_in[b,c] )
// ---------------------------------------------------------------------------
__global__ __launch_bounds__(256) void fixup_scan(const float* __restrict__ hs,
                                                  unsigned short* __restrict__ hs_bf,
                                                  const float* __restrict__ PowLayer,
                                                  const float* __restrict__ carry) {
    int t = blockIdx.x;   // 0..Qc-1
    int c = blockIdx.y;   // 0..NCHUNK-1
    const float* P = PowLayer + (size_t)(t + 1) * (Sn * Sn);
    __shared__ float Pl[Sn * 65];   // half of P (k-halves), padded
    __shared__ float cl[Bn * Sn];
    int tid = threadIdx.x;
    for (int idx = tid; idx < Bn * Sn; idx += 256)
        cl[idx] = carry[((size_t)(idx >> 7) * NCHUNK + c) * Sn + (idx & 127)];
    int s = tid & 127, bh = tid >> 7;
    float acc[4] = {0.f, 0.f, 0.f, 0.f};
    for (int kh = 0; kh < 2; kh++) {
        __syncthreads();
        for (int idx = tid; idx < Sn * 64; idx += 256) {
            int r = idx >> 6, kk = idx & 63;
            Pl[r * 65 + kk] = P[(size_t)r * Sn + kh * 64 + kk];
        }
        __syncthreads();
        for (int kk = 0; kk < 64; kk++) {
            float pw = Pl[s * 65 + kk];
            int kg = kh * 64 + kk;
#pragma unroll
            for (int j = 0; j < 4; j++)
                acc[j] += pw * cl[(bh * 4 + j) * Sn + kg];
        }
    }
#pragma unroll
    for (int j = 0; j < 4; j++) {
        int bb = bh * 4 + j;
        size_t rowi = (size_t)(bb * Lseq + c * Qc + t) * Sn + s;
        hs_bf[rowi] = f2bf(hs[rowi] + acc[j]);
    }
}

// ---------------------------------------------------------------------------
extern "C" void kernel_launch(void* const* d_in, const int* in_sizes, int n_in,
                              void* d_out, int out_size, void* d_ws, size_t ws_size,
                              hipStream_t stream) {
    const float* x     = (const float*)d_in[0];
    const float* Am    = (const float*)d_in[1];
    const float* Bp    = (const float*)d_in[2];
    const float* Cp    = (const float*)d_in[3];
    const float* Dp    = (const float*)d_in[4];
    const float* Wi    = (const float*)d_in[5];
    const float* bi    = (const float*)d_in[6];
    const float* Wo    = (const float*)d_in[7];
    const float* bo    = (const float*)d_in[8];
    const float* gamma = (const float*)d_in[9];
    const float* beta  = (const float*)d_in[10];
    float* out = (float*)d_out;
    (void)in_sizes; (void)n_in; (void)out_size; (void)ws_size;

    // Workspace layout (~107.4 MB)
    char* ws = (char*)d_ws;
    float*          seq   = (float*)(ws + (size_t)0);                 // 32 MB
    unsigned short* nbuf  = (unsigned short*)(ws + (size_t)33554432); // 16 MB
    // precompute-phase aliases inside nbuf region (dead before first ln):
    unsigned short* WiTh  = (unsigned short*)(ws + (size_t)33554432); //  8 MB
    unsigned short* Woh   = (unsigned short*)(ws + (size_t)41943040); //  8 MB
    unsigned short* u     = (unsigned short*)(ws + (size_t)50331648); // 16 MB
    float*          ub    = (float*)(ws + (size_t)67108864);          //  4 MB
    float*          hs    = (float*)(ws + (size_t)71303168);          //  4 MB
    unsigned short* hs_bf = (unsigned short*)(ws + (size_t)75497472); //  2 MB
    float*          Pow   = (float*)(ws + (size_t)77594624);          //  8.25 MB
    float*          carry = (float*)(ws + (size_t)86245376);          //  128 KB
    unsigned short* Wih   = (unsigned short*)(ws + (size_t)86376448); //  8 MB
    unsigned short* Wo2h  = (unsigned short*)(ws + (size_t)94765056); //  8 MB (Wo*Dp)
    unsigned short* Bph   = (unsigned short*)(ws + (size_t)103153664);//  1 MB
    unsigned short* CpTh  = (unsigned short*)(ws + (size_t)104202240);//  1 MB
    unsigned short* M2h   = (unsigned short*)(ws + (size_t)105250816);//  1 MB (DT*Bp@Wi)
    unsigned short* W3h   = (unsigned short*)(ws + (size_t)106299392);//  1 MB (Wo@Cp)
    float*          c2dt  = (float*)(ws + (size_t)107347968);         //  2 KB

    const long WW = (long)Dm * Dm;     // 1M
    const long SW = (long)Sn * Dm;     // 128K

    // ---- precompute: converts ----
    hipLaunchKernelGGL(f2bf_kernel, dim3(DEPTH * WW / 1024), dim3(256), 0, stream,
                       Wi, Wih, DEPTH * (int)WW);
    hipLaunchKernelGGL(f2bf_kernel, dim3(DEPTH * WW / 1024), dim3(256), 0, stream,
                       Wo, Woh, DEPTH * (int)WW);
    hipLaunchKernelGGL(f2bf_kernel, dim3(DEPTH * SW / 1024), dim3(256), 0, stream,
                       Bp, Bph, DEPTH * (int)SW);
    hipLaunchKernelGGL(convscale_kernel, dim3(WW / 1024, DEPTH), dim3(256), 0, stream,
                       Wo, Dp, Wo2h);
    hipLaunchKernelGGL(transpose_f2bf, dim3(32, 32, DEPTH), dim3(256), 0, stream,
                       Wi, WiTh, Dm, Dm);
    hipLaunchKernelGGL(transpose_f2bf, dim3(4, 32, DEPTH), dim3(256), 0, stream,
                       Cp, CpTh, Dm, Sn);
    hipLaunchKernelGGL(c2dt_kernel, dim3(DEPTH, Sn), dim3(256), 0, stream, Bp, bi, c2dt);

    // ---- precompute GEMMs (mode 2, z-batched over layers) ----
    // M2h[z] = bf16(DT * Bph[z] @ WiTh[z]^T)  : M=128, N=1024, K=1024
    hipLaunchKernelGGL(gemm_bk64, dim3(8, DEPTH), dim3(256), 0, stream,
                       Bph, Dm, (const unsigned short*)nullptr, 0, 0,
                       WiTh, Dm, (const unsigned short*)nullptr, 0,
                       (float*)nullptr, M2h, (const float*)nullptr, (const float*)nullptr,
                       1, Dm, Dm, DT_STEP, 2, SW, WW, SW);
    // W3h[z] = bf16(Woh[z] @ CpTh[z]^T)       : M=1024, N=128, K=1024
    hipLaunchKernelGGL(gemm_bk64, dim3(8, DEPTH), dim3(256), 0, stream,
                       Woh, Dm, (const unsigned short*)nullptr, 0, 0,
                       CpTh, Dm, (const unsigned short*)nullptr, 0,
                       (float*)nullptr, W3h, (const float*)nullptr, (const float*)nullptr,
                       8, Sn, Dm, 1.f, 2, WW, SW, SW);

    // x (B,C,HW) -> seq (B,HW,C)
    hipLaunchKernelGGL(transpose_bll, dim3(32, 32, Bn), dim3(32, 32), 0, stream, x, seq);

    // Matrix powers of A_bar for all layers: I, A^1, then log-doubling
    hipLaunchKernelGGL(pow_init, dim3(DEPTH, Sn), dim3(Sn), 0, stream, Am, Pow);
    for (int m = 1; m < Qc; m <<= 1) {
        hipLaunchKernelGGL(pow_mul, dim3(4, 2, DEPTH * m), dim3(16, 16), 0, stream,
                           Pow, m, m);
    }

    for (int i = 0; i < DEPTH; i++) {
        const unsigned short* Wi_i  = Wih  + (size_t)i * WW;
        const unsigned short* Wo2_i = Wo2h + (size_t)i * WW;
        const unsigned short* M2_i  = M2h  + (size_t)i * SW;
        const unsigned short* W3_i  = W3h  + (size_t)i * SW;
        const float* PowL = Pow + (size_t)i * NPOW * (Sn * Sn);

        hipLaunchKernelGGL(ln_kernel, dim3(Mrows), dim3(256), 0, stream,
                           seq, nbuf, gamma + i * Dm, beta + i * Dm);
        // fused u+ub: [u | ub] = n @ [Wi | M2]^T ; N=1152, grid 9*64 flat
        hipLaunchKernelGGL(gemm_bk64, dim3(9 * 64, 1), dim3(256), 0, stream,
                           nbuf, Dm, (const unsigned short*)nullptr, 0, 0,
                           Wi_i, Dm, M2_i, Dm,
                           ub, u, bi + i * Dm, c2dt + i * Sn,
                           64, Dm + Sn, Dm, 1.f, 0, 0, 0, 0);
        // chunked scan
        hipLaunchKernelGGL(local_scan, dim3(Bn * NCHUNK), dim3(Sn), 0, stream,
                           ub, hs, PowL + (size_t)1 * Sn * Sn);
        hipLaunchKernelGGL(carry_scan, dim3(Bn), dim3(Sn), 0, stream,
                           hs, PowL + (size_t)Qc * Sn * Sn, carry);
        hipLaunchKernelGGL(fixup_scan, dim3(Qc, NCHUNK), dim3(256), 0, stream,
                           hs, hs_bf, PowL, carry);
        // fused output: seq += [hs | u] @ [W3 | Wo*Dp]^T + bo ; K=1152
        hipLaunchKernelGGL(gemm_bk64, dim3(8 * 64, 1), dim3(256), 0, stream,
                           hs_bf, Sn, u, Dm, Sn,
                           W3_i, Sn, Wo2_i, Dm,
                           seq, (unsigned short*)nullptr, bo + i * Dm, (const float*)nullptr,
                           64, Dm, Dm + Sn, 1.f, 1, 0, 0, 0);
    }

    // seq (B,HW,C) -> out (B,C,HW)
    hipLaunchKernelGGL(transpose_bll, dim3(32, 32, Bn), dim3(32, 32), 0, stream, seq, out);
}

// Round 5
// 812.169 us; speedup vs baseline: 1.1724x; 1.1724x over previous
//
#include <hip/hip_runtime.h>
#include <stdint.h>

// Problem constants (MambaBlock: B=8, C=d=1024, H*W=L=1024, depth=4, S=128)
#define DT_STEP 0.001f
#define LN_EPS  1e-5f
#define Bn      8
#define Lseq    1024
#define Dm      1024
#define Sn      128
#define DEPTH   4
#define Mrows   (Bn * Lseq)       // 8192
#define Qc      32                // scan chunk size
#define NCHUNK  (Lseq / Qc)       // 32
#define NPOW    33                // powers 0..32 per layer

typedef short bf16x8 __attribute__((ext_vector_type(8)));
typedef float f32x4  __attribute__((ext_vector_type(4)));

__device__ __forceinline__ unsigned short f2bf(float f) {
    unsigned int u = __float_as_uint(f);
    u += 0x7fffu + ((u >> 16) & 1u);          // round-to-nearest-even
    return (unsigned short)(u >> 16);
}

// async 16B global->LDS (wave-uniform LDS base + lane*16; slot linear in lane)
#define GLOAD_LDS16(gp, lp)                                                \
    __builtin_amdgcn_global_load_lds(                                      \
        (const __attribute__((address_space(1))) unsigned int*)(gp),       \
        (__attribute__((address_space(3))) unsigned int*)(lp), 16, 0, 0)

// ---------------------------------------------------------------------------
// fp32 -> bf16 elementwise convert (n multiple of 1024)
// ---------------------------------------------------------------------------
__global__ __launch_bounds__(256) void f2bf_kernel(const float* __restrict__ src,
                                                   unsigned short* __restrict__ dst,
                                                   int n) {
    int i = (blockIdx.x * 256 + threadIdx.x) * 4;
    if (i < n) {
        float4 v = *(const float4*)(src + i);
        ushort4 o;
        o.x = f2bf(v.x); o.y = f2bf(v.y); o.z = f2bf(v.z); o.w = f2bf(v.w);
        *(ushort4*)(dst + i) = o;
    }
}

// Wo2[j,k] = bf16(Wo[j,k] * Dp[k])  (per-layer z)
__global__ __launch_bounds__(256) void convscale_kernel(const float* __restrict__ Wo,
                                                        const float* __restrict__ Dp,
                                                        unsigned short* __restrict__ dst) {
    int z = blockIdx.y;
    int i = (blockIdx.x * 256 + threadIdx.x) * 4;
    const float* S = Wo + (size_t)z * Dm * Dm;
    const float* dp = Dp + (size_t)z * Dm;
    float4 v = *(const float4*)(S + i);
    int c = i & (Dm - 1);
    float4 d = *(const float4*)(dp + c);
    ushort4 o;
    o.x = f2bf(v.x * d.x); o.y = f2bf(v.y * d.y);
    o.z = f2bf(v.z * d.z); o.w = f2bf(v.w * d.w);
    *(ushort4*)(dst + (size_t)z * Dm * Dm + i) = o;
}

// transpose+convert: src (R x C) fp32 -> dst (C x R) bf16, batched z
__global__ __launch_bounds__(256) void transpose_f2bf(const float* __restrict__ src,
                                                      unsigned short* __restrict__ dst,
                                                      int R, int C) {
    __shared__ float t[32][33];
    int z = blockIdx.z;
    const float* S = src + (size_t)z * R * C;
    unsigned short* D = dst + (size_t)z * R * C;
    int r0 = blockIdx.y * 32, c0 = blockIdx.x * 32;
    int tx = threadIdx.x & 31, ty = threadIdx.x >> 5;   // 32 x 8
    for (int rr = ty; rr < 32; rr += 8)
        t[rr][tx] = S[(size_t)(r0 + rr) * C + c0 + tx];
    __syncthreads();
    for (int rr = ty; rr < 32; rr += 8)
        D[(size_t)(c0 + rr) * R + r0 + tx] = f2bf(t[tx][rr]);
}

// c2dt[z*Sn+s] = DT * sum_j Bp[z,s,j]*bi[z,j]
__global__ __launch_bounds__(256) void c2dt_kernel(const float* __restrict__ Bp,
                                                   const float* __restrict__ bi,
                                                   float* __restrict__ c2dt) {
    int z = blockIdx.x, s = blockIdx.y;
    int tid = threadIdx.x;
    const float* br = Bp + ((size_t)z * Sn + s) * Dm;
    const float* bb = bi + (size_t)z * Dm;
    float4 v = *(const float4*)(br + tid * 4);
    float4 w = *(const float4*)(bb + tid * 4);
    float acc = v.x * w.x + v.y * w.y + v.z * w.z + v.w * w.w;
#pragma unroll
    for (int off = 32; off > 0; off >>= 1) acc += __shfl_down(acc, off, 64);
    __shared__ float red[4];
    if ((tid & 63) == 0) red[tid >> 6] = acc;
    __syncthreads();
    if (tid == 0) c2dt[z * Sn + s] = DT_STEP * (red[0] + red[1] + red[2] + red[3]);
}

// ---------------------------------------------------------------------------
// Batched 1024x1024 transpose fp32: dst[b][i][j] = src[b][j][i]
// ---------------------------------------------------------------------------
__global__ __launch_bounds__(1024) void transpose_bll(const float* __restrict__ src,
                                                      float* __restrict__ dst) {
    __shared__ float tile[32][33];
    int b  = blockIdx.z;
    int i0 = blockIdx.y * 32, j0 = blockIdx.x * 32;
    int tx = threadIdx.x, ty = threadIdx.y;
    const float* S = src + (size_t)b * Dm * Lseq;
    float*       D = dst + (size_t)b * Dm * Lseq;
    tile[ty][tx] = S[(size_t)(j0 + ty) * 1024 + i0 + tx];
    __syncthreads();
    D[(size_t)(i0 + ty) * 1024 + j0 + tx] = tile[tx][ty];
}

// ---------------------------------------------------------------------------
// Row LayerNorm, bf16 output
// ---------------------------------------------------------------------------
__global__ __launch_bounds__(256) void ln_kernel(const float* __restrict__ x,
                                                 unsigned short* __restrict__ outp,
                                                 const float* __restrict__ g,
                                                 const float* __restrict__ bta) {
    int row = blockIdx.x;
    int tid = threadIdx.x;
    const float* xr = x + (size_t)row * Dm;
    float4 v = *(const float4*)(xr + tid * 4);
    float s  = v.x + v.y + v.z + v.w;
    float ss = v.x * v.x + v.y * v.y + v.z * v.z + v.w * v.w;
#pragma unroll
    for (int off = 32; off > 0; off >>= 1) {
        s  += __shfl_down(s, off, 64);
        ss += __shfl_down(ss, off, 64);
    }
    __shared__ float red[8];
    __shared__ float mv[2];
    int wave = tid >> 6, lane = tid & 63;
    if (lane == 0) { red[wave] = s; red[4 + wave] = ss; }
    __syncthreads();
    if (tid == 0) {
        float st  = red[0] + red[1] + red[2] + red[3];
        float sst = red[4] + red[5] + red[6] + red[7];
        float mean = st / (float)Dm;
        float var  = sst / (float)Dm - mean * mean;
        mv[0] = mean;
        mv[1] = rsqrtf(var + LN_EPS);
    }
    __syncthreads();
    float mean = mv[0], rstd = mv[1];
    int c = tid * 4;
    float4 gv = *(const float4*)(g + c);
    float4 bv = *(const float4*)(bta + c);
    ushort4 o;
    o.x = f2bf((v.x - mean) * rstd * gv.x + bv.x);
    o.y = f2bf((v.y - mean) * rstd * gv.y + bv.y);
    o.z = f2bf((v.z - mean) * rstd * gv.z + bv.z);
    o.w = f2bf((v.w - mean) * rstd * gv.w + bv.w);
    *(ushort4*)(outp + (size_t)row * Dm + c) = o;
}

// ---------------------------------------------------------------------------
// NT GEMM, BK=64, bf16 MFMA, XOR-swizzled LDS, global_load_lds staging.
// 512 threads = 8 waves (2x4 over the 128x128 tile; 64x32 per wave) -- doubles
// waves/CU vs the 4-wave version to hide the 2-barrier K-loop's vmcnt drain
// with cross-wave overlap (R4's explicit-pipeline attempt regressed: compiler
// stacks its own waitcnts on inline-asm gates, and 64KB LDS cut blocks/CU).
// Grid: 1-D flat, row_blk = flat % ny, col_blk = flat / ny  (XCD A-reuse).
// modes: 0 fused u+ub, 1 fused-K output+residual, 2 precompute (z-batched)
// ---------------------------------------------------------------------------
__global__ __launch_bounds__(512) void gemm_bk64(
    const unsigned short* __restrict__ A1, int sA1,
    const unsigned short* __restrict__ A2, int sA2, int KA1,
    const unsigned short* __restrict__ B1, int sB1,
    const unsigned short* __restrict__ B2, int sB2,
    float* __restrict__ Cf, unsigned short* __restrict__ Ch,
    const float* __restrict__ bias1, const float* __restrict__ bias2,
    int ny, int N, int K, float scale, int mode,
    long batchA, long batchB, long batchC) {
    __shared__ __align__(16) unsigned short As[1024 * 8]; // 128 rows x 8 kchunks x 8
    __shared__ __align__(16) unsigned short Bs[1024 * 8];
    int flat = blockIdx.x;
    int rb = flat % ny, cb = flat / ny;
    int row0 = rb * 128, col0 = cb * 128;
    int z = blockIdx.y;
    int tid  = threadIdx.x;
    int wave = tid >> 6, lane = tid & 63;
    int wm = (wave & 1) * 64, wn = (wave >> 1) * 32;
    int lr = lane & 15, lq = lane >> 4;

    // staging slots: s = tid + q*512; row = s>>3, phys kchunk = s&7,
    // logical kchunk = (s&7) ^ (row&7); LDS dest slot*16B linear in lane.
    int rowS[2], kclS[2], slotOff[2];
#pragma unroll
    for (int q = 0; q < 2; q++) {
        int s = tid + q * 512;
        rowS[q] = s >> 3;
        kclS[q] = (s & 7) ^ ((s >> 3) & 7);
        slotOff[q] = s * 8;
    }
    // fragment LDS offsets (shorts): slot = row*8 + ((lq+4h) ^ (row&7))
    int aoff[4][2], boff[2][2];
#pragma unroll
    for (int i = 0; i < 4; i++)
#pragma unroll
        for (int h = 0; h < 2; h++) {
            int ra = wm + i * 16 + lr;
            aoff[i][h] = (ra * 8 + ((lq + 4 * h) ^ (ra & 7))) * 8;
        }
#pragma unroll
    for (int j = 0; j < 2; j++)
#pragma unroll
        for (int h = 0; h < 2; h++) {
            int rn = wn + j * 16 + lr;
            boff[j][h] = (rn * 8 + ((lq + 4 * h) ^ (rn & 7))) * 8;
        }

    // pre-resolve fixed operands
    const unsigned short* A1b = A1 + (size_t)z * batchA;
    const unsigned short* BfixBlk = nullptr;
    int sBfix = sB1;
    if (mode == 0) {
        if (col0 < N - 128) { BfixBlk = B1 + (size_t)col0 * sB1; sBfix = sB1; }
        else                { BfixBlk = B2;                      sBfix = sB2; }
    } else if (mode == 2) {
        BfixBlk = B1 + (size_t)z * batchB + (size_t)col0 * sB1;
        sBfix = sB1;
    }

    f32x4 acc[4][2];
#pragma unroll
    for (int i = 0; i < 4; i++)
#pragma unroll
        for (int j = 0; j < 2; j++) acc[i][j] = (f32x4){0.f, 0.f, 0.f, 0.f};

    for (int k0 = 0; k0 < K; k0 += 64) {
        const unsigned short *Ab, *Bb;
        int sa, sb, ko;
        if (mode == 1) {
            if (k0 < KA1) { Ab = A1; sa = sA1; Bb = B1 + (size_t)col0 * sB1; sb = sB1; ko = k0; }
            else          { Ab = A2; sa = sA2; Bb = B2 + (size_t)col0 * sB2; sb = sB2; ko = k0 - KA1; }
        } else {
            Ab = A1b; sa = sA1; Bb = BfixBlk; sb = sBfix; ko = k0;
        }
        const unsigned short* Abr = Ab + (size_t)row0 * sa + ko;
        const unsigned short* Bbr = Bb + ko;
        __syncthreads();
#pragma unroll
        for (int q = 0; q < 2; q++) {
            GLOAD_LDS16(Abr + (size_t)rowS[q] * sa + kclS[q] * 8, &As[slotOff[q]]);
            GLOAD_LDS16(Bbr + (size_t)rowS[q] * sb + kclS[q] * 8, &Bs[slotOff[q]]);
        }
        __syncthreads();
#pragma unroll
        for (int h = 0; h < 2; h++) {
            bf16x8 af[4], bfr[2];
#pragma unroll
            for (int i = 0; i < 4; i++) af[i]  = *(const bf16x8*)&As[aoff[i][h]];
#pragma unroll
            for (int j = 0; j < 2; j++) bfr[j] = *(const bf16x8*)&Bs[boff[j][h]];
#pragma unroll
            for (int i = 0; i < 4; i++)
#pragma unroll
                for (int j = 0; j < 2; j++)
                    acc[i][j] = __builtin_amdgcn_mfma_f32_16x16x32_bf16(af[i], bfr[j],
                                                                       acc[i][j], 0, 0, 0);
        }
    }
    // Epilogue. C/D layout: row = lq*4 + r, col = lr (m89-verified)
#pragma unroll
    for (int i = 0; i < 4; i++) {
#pragma unroll
        for (int j = 0; j < 2; j++) {
#pragma unroll
            for (int r = 0; r < 4; r++) {
                int row = row0 + wm + i * 16 + lq * 4 + r;
                int col = col0 + wn + j * 16 + lr;
                float v = acc[i][j][r];
                if (mode == 0) {
                    int nu = N - 128;
                    if (col < nu) {
                        Ch[(size_t)row * nu + col] = f2bf(v + bias1[col]);
                    } else {
                        int cc = col - nu;
                        Cf[(size_t)row * 128 + cc] = v + bias2[cc];
                    }
                } else if (mode == 1) {
                    size_t idx = (size_t)row * N + col;
                    Cf[idx] = Cf[idx] + v + bias1[col];
                } else {
                    Ch[(size_t)z * batchC + (size_t)row * N + col] = f2bf(v * scale);
                }
            }
        }
    }
}

// ---------------------------------------------------------------------------
// Matrix powers of A_bar = I + DT*A (fp32 — bf16 would erase the DT*A part!)
// ---------------------------------------------------------------------------
__global__ __launch_bounds__(128) void pow_init(const float* __restrict__ Amat,
                                                float* __restrict__ Pow) {
    int i = blockIdx.x;   // layer
    int s = blockIdx.y;   // row
    int k = threadIdx.x;  // col
    float eye = (s == k) ? 1.f : 0.f;
    size_t base = (size_t)i * NPOW * (Sn * Sn);
    Pow[base + (size_t)s * Sn + k] = eye;  // A^0 = I
    Pow[base + (size_t)(Sn * Sn) + (size_t)s * Sn + k] =
        eye + DT_STEP * Amat[(size_t)i * Sn * Sn + (size_t)s * Sn + k];
}

// Pc = Pa @ Pb, each 128x128 fp32. Block computes 64x32 quadrant.
__global__ __launch_bounds__(256) void pow_mul(float* __restrict__ Pow, int m, int kmax) {
    int job = blockIdx.z;
    int i  = job / kmax;
    int kk = job % kmax + 1;
    const float* Pa = Pow + ((size_t)i * NPOW + m) * (Sn * Sn);
    const float* Pb = Pow + ((size_t)i * NPOW + kk) * (Sn * Sn);
    float*       Pc = Pow + ((size_t)i * NPOW + m + kk) * (Sn * Sn);
    int r0 = blockIdx.y * 64, c0 = blockIdx.x * 32;
    __shared__ float Asl[64 * 129];
    __shared__ float Bsl[128 * 32];
    int tx = threadIdx.x, ty = threadIdx.y;
    int tid = ty * 16 + tx;
    for (int idx = tid; idx < 64 * 128; idx += 256) {
        int r = idx >> 7, cc = idx & 127;
        Asl[r * 129 + cc] = Pa[(size_t)(r0 + r) * 128 + cc];
    }
    for (int idx = tid; idx < 128 * 32; idx += 256) {
        int r = idx >> 5, cc = idx & 31;
        Bsl[r * 32 + cc] = Pb[(size_t)r * 128 + c0 + cc];
    }
    __syncthreads();
    float acc[4][2] = {{0.f,0.f},{0.f,0.f},{0.f,0.f},{0.f,0.f}};
    for (int k = 0; k < 128; k++) {
        float b0 = Bsl[k * 32 + tx * 2];
        float b1 = Bsl[k * 32 + tx * 2 + 1];
#pragma unroll
        for (int r = 0; r < 4; r++) {
            float a = Asl[(ty * 4 + r) * 129 + k];
            acc[r][0] += a * b0;
            acc[r][1] += a * b1;
        }
    }
#pragma unroll
    for (int r = 0; r < 4; r++) {
        Pc[(size_t)(r0 + ty * 4 + r) * 128 + c0 + tx * 2]     = acc[r][0];
        Pc[(size_t)(r0 + ty * 4 + r) * 128 + c0 + tx * 2 + 1] = acc[r][1];
    }
}

// ---------------------------------------------------------------------------
// Chunk-local scan: per (b, chunk) block, h_t = A_bar@h_{t-1} + ub_t from h=0
// ---------------------------------------------------------------------------
__global__ __launch_bounds__(128) void local_scan(const float* __restrict__ ub,
                                                  float* __restrict__ hs,
                                                  const float* __restrict__ Abar) {
    int b = blockIdx.x / NCHUNK;
    int c = blockIdx.x % NCHUNK;
    int s = threadIdx.x;
    float arow[Sn];
#pragma unroll
    for (int k = 0; k < Sn; k += 4) {
        float4 v = *(const float4*)(Abar + (size_t)s * Sn + k);
        arow[k] = v.x; arow[k + 1] = v.y; arow[k + 2] = v.z; arow[k + 3] = v.w;
    }
    __shared__ __align__(16) float hsh[Sn];
    hsh[s] = 0.f;
    __syncthreads();
    size_t base = (size_t)(b * Lseq + c * Qc) * Sn + s;
    for (int t = 0; t < Qc; t++) {
        float ut = ub[base + (size_t)t * Sn];
        float a0 = 0.f, a1 = 0.f, a2 = 0.f, a3 = 0.f;
#pragma unroll
        for (int k = 0; k < Sn; k += 16) {
            float4 h0 = *(const float4*)&hsh[k];
            float4 h1 = *(const float4*)&hsh[k + 4];
            float4 h2 = *(const float4*)&hsh[k + 8];
            float4 h3 = *(const float4*)&hsh[k + 12];
            a0 += arow[k + 0] * h0.x + arow[k + 1] * h0.y + arow[k + 2] * h0.z + arow[k + 3] * h0.w;
            a1 += arow[k + 4] * h1.x + arow[k + 5] * h1.y + arow[k + 6] * h1.z + arow[k + 7] * h1.w;
            a2 += arow[k + 8] * h2.x + arow[k + 9] * h2.y + arow[k + 10] * h2.z + arow[k + 11] * h2.w;
            a3 += arow[k + 12] * h3.x + arow[k + 13] * h3.y + arow[k + 14] * h3.z + arow[k + 15] * h3.w;
        }
        float hv = ut + (a0 + a1) + (a2 + a3);
        hs[base + (size_t)t * Sn] = hv;
        __syncthreads();
        hsh[s] = hv;
        __syncthreads();
    }
}

// ---------------------------------------------------------------------------
// Cross-chunk carry scan with up-front prefetch of all chunk-end states.
// ---------------------------------------------------------------------------
__global__ __launch_bounds__(128) void carry_scan(const float* __restrict__ hs,
                                                  const float* __restrict__ AQ,
                                                  float* __restrict__ carry) {
    int b = blockIdx.x;
    int s = threadIdx.x;
    float le[NCHUNK];
#pragma unroll
    for (int c = 0; c < NCHUNK; c++)
        le[c] = hs[(size_t)(b * Lseq + c * Qc + Qc - 1) * Sn + s];
    float arow[Sn];
#pragma unroll
    for (int k = 0; k < Sn; k += 4) {
        float4 v = *(const float4*)(AQ + (size_t)s * Sn + k);
        arow[k] = v.x; arow[k + 1] = v.y; arow[k + 2] = v.z; arow[k + 3] = v.w;
    }
    __shared__ __align__(16) float csh[Sn];
    csh[s] = 0.f;
    __syncthreads();
    for (int c = 0; c < NCHUNK; c++) {
        carry[((size_t)b * NCHUNK + c) * Sn + s] = csh[s];
        float a0 = 0.f, a1 = 0.f, a2 = 0.f, a3 = 0.f;
#pragma unroll
        for (int k = 0; k < Sn; k += 16) {
            float4 h0 = *(const float4*)&csh[k];
            float4 h1 = *(const float4*)&csh[k + 4];
            float4 h2 = *(const float4*)&csh[k + 8];
            float4 h3 = *(const float4*)&csh[k + 12];
            a0 += arow[k + 0] * h0.x + arow[k + 1] * h0.y + arow[k + 2] * h0.z + arow[k + 3] * h0.w;
            a1 += arow[k + 4] * h1.x + arow[k + 5] * h1.y + arow[k + 6] * h1.z + arow[k + 7] * h1.w;
            a2 += arow[k + 8] * h2.x + arow[k + 9] * h2.y + arow[k + 10] * h2.z + arow[k + 11] * h2.w;
            a3 += arow[k + 12] * h3.x + arow[k + 13] * h3.y + arow[k + 14] * h3.z + arow[k + 15] * h3.w;
        }
        float cv = le[c] + (a0 + a1) + (a2 + a3);
        __syncthreads();
        csh[s] = cv;
        __syncthreads();
    }
}

// ---------------------------------------------------------------------------
// Fixup: hs_bf[b, c*Q+t, :] = bf16( hs[b,c*Q+t,:] + A^(t+1) @ carry_in[b,c] )
// Block = (t, 4 chunks): P(t+1) staged once in LDS, reused for 4 chunks ->
// P traffic 64 MB -> 16 MB per layer.
// ---------------------------------------------------------------------------
__global__ __launch_bounds__(256) void fixup_scan(const float* __restrict__ hs,
                                                  unsigned short* __restrict__ hs_bf,
                                                  const float* __restrict__ PowLayer,
                                                  const float* __restrict__ carry) {
    int t  = blockIdx.x;   // 0..Qc-1
    int c4 = blockIdx.y;   // 0..NCHUNK/4-1
    const float* P = PowLayer + (size_t)(t + 1) * (Sn * Sn);
    __shared__ float Pl[Sn * 65];       // half of P (k-halves), padded (~33 KB)
    __shared__ float cl[4][Bn * Sn];    // carries for 4 chunks (16 KB)
    int tid = threadIdx.x;
#pragma unroll
    for (int cc = 0; cc < 4; cc++)
        for (int idx = tid; idx < Bn * Sn; idx += 256)
            cl[cc][idx] = carry[((size_t)(idx >> 7) * NCHUNK + (c4 * 4 + cc)) * Sn + (idx & 127)];
    int s = tid & 127, bh = tid >> 7;
    float acc[4][4];   // [chunk][batch-sub]
#pragma unroll
    for (int cc = 0; cc < 4; cc++)
#pragma unroll
        for (int j = 0; j < 4; j++) acc[cc][j] = 0.f;
    for (int kh = 0; kh < 2; kh++) {
        __syncthreads();
        for (int idx = tid; idx < Sn * 64; idx += 256) {
            int r = idx >> 6, kk = idx & 63;
            Pl[r * 65 + kk] = P[(size_t)r * Sn + kh * 64 + kk];
        }
        __syncthreads();
        for (int kk = 0; kk < 64; kk++) {
            float pw = Pl[s * 65 + kk];
            int kg = kh * 64 + kk;
#pragma unroll
            for (int cc = 0; cc < 4; cc++)
#pragma unroll
                for (int j = 0; j < 4; j++)
                    acc[cc][j] += pw * cl[cc][(bh * 4 + j) * Sn + kg];
        }
    }
#pragma unroll
    for (int cc = 0; cc < 4; cc++) {
        int c = c4 * 4 + cc;
#pragma unroll
        for (int j = 0; j < 4; j++) {
            int bb = bh * 4 + j;
            size_t rowi = (size_t)(bb * Lseq + c * Qc + t) * Sn + s;
            hs_bf[rowi] = f2bf(hs[rowi] + acc[cc][j]);
        }
    }
}

// ---------------------------------------------------------------------------
extern "C" void kernel_launch(void* const* d_in, const int* in_sizes, int n_in,
                              void* d_out, int out_size, void* d_ws, size_t ws_size,
                              hipStream_t stream) {
    const float* x     = (const float*)d_in[0];
    const float* Am    = (const float*)d_in[1];
    const float* Bp    = (const float*)d_in[2];
    const float* Cp    = (const float*)d_in[3];
    const float* Dp    = (const float*)d_in[4];
    const float* Wi    = (const float*)d_in[5];
    const float* bi    = (const float*)d_in[6];
    const float* Wo    = (const float*)d_in[7];
    const float* bo    = (const float*)d_in[8];
    const float* gamma = (const float*)d_in[9];
    const float* beta  = (const float*)d_in[10];
    float* out = (float*)d_out;
    (void)in_sizes; (void)n_in; (void)out_size; (void)ws_size;

    // Workspace layout (~107.4 MB)
    char* ws = (char*)d_ws;
    float*          seq   = (float*)(ws + (size_t)0);                 // 32 MB
    unsigned short* nbuf  = (unsigned short*)(ws + (size_t)33554432); // 16 MB
    // precompute-phase aliases inside nbuf region (dead before first ln):
    unsigned short* WiTh  = (unsigned short*)(ws + (size_t)33554432); //  8 MB
    unsigned short* Woh   = (unsigned short*)(ws + (size_t)41943040); //  8 MB
    unsigned short* u     = (unsigned short*)(ws + (size_t)50331648); // 16 MB
    float*          ub    = (float*)(ws + (size_t)67108864);          //  4 MB
    float*          hs    = (float*)(ws + (size_t)71303168);          //  4 MB
    unsigned short* hs_bf = (unsigned short*)(ws + (size_t)75497472); //  2 MB
    float*          Pow   = (float*)(ws + (size_t)77594624);          //  8.25 MB
    float*          carry = (float*)(ws + (size_t)86245376);          //  128 KB
    unsigned short* Wih   = (unsigned short*)(ws + (size_t)86376448); //  8 MB
    unsigned short* Wo2h  = (unsigned short*)(ws + (size_t)94765056); //  8 MB (Wo*Dp)
    unsigned short* Bph   = (unsigned short*)(ws + (size_t)103153664);//  1 MB
    unsigned short* CpTh  = (unsigned short*)(ws + (size_t)104202240);//  1 MB
    unsigned short* M2h   = (unsigned short*)(ws + (size_t)105250816);//  1 MB (DT*Bp@Wi)
    unsigned short* W3h   = (unsigned short*)(ws + (size_t)106299392);//  1 MB (Wo@Cp)
    float*          c2dt  = (float*)(ws + (size_t)107347968);         //  2 KB

    const long WW = (long)Dm * Dm;     // 1M
    const long SW = (long)Sn * Dm;     // 128K

    // ---- precompute: converts ----
    hipLaunchKernelGGL(f2bf_kernel, dim3(DEPTH * WW / 1024), dim3(256), 0, stream,
                       Wi, Wih, DEPTH * (int)WW);
    hipLaunchKernelGGL(f2bf_kernel, dim3(DEPTH * WW / 1024), dim3(256), 0, stream,
                       Wo, Woh, DEPTH * (int)WW);
    hipLaunchKernelGGL(f2bf_kernel, dim3(DEPTH * SW / 1024), dim3(256), 0, stream,
                       Bp, Bph, DEPTH * (int)SW);
    hipLaunchKernelGGL(convscale_kernel, dim3(WW / 1024, DEPTH), dim3(256), 0, stream,
                       Wo, Dp, Wo2h);
    hipLaunchKernelGGL(transpose_f2bf, dim3(32, 32, DEPTH), dim3(256), 0, stream,
                       Wi, WiTh, Dm, Dm);
    hipLaunchKernelGGL(transpose_f2bf, dim3(4, 32, DEPTH), dim3(256), 0, stream,
                       Cp, CpTh, Dm, Sn);
    hipLaunchKernelGGL(c2dt_kernel, dim3(DEPTH, Sn), dim3(256), 0, stream, Bp, bi, c2dt);

    // ---- precompute GEMMs (mode 2, z-batched over layers) ----
    // M2h[z] = bf16(DT * Bph[z] @ WiTh[z]^T)  : M=128, N=1024, K=1024
    hipLaunchKernelGGL(gemm_bk64, dim3(8, DEPTH), dim3(512), 0, stream,
                       Bph, Dm, (const unsigned short*)nullptr, 0, 0,
                       WiTh, Dm, (const unsigned short*)nullptr, 0,
                       (float*)nullptr, M2h, (const float*)nullptr, (const float*)nullptr,
                       1, Dm, Dm, DT_STEP, 2, SW, WW, SW);
    // W3h[z] = bf16(Woh[z] @ CpTh[z]^T)       : M=1024, N=128, K=1024
    hipLaunchKernelGGL(gemm_bk64, dim3(8, DEPTH), dim3(512), 0, stream,
                       Woh, Dm, (const unsigned short*)nullptr, 0, 0,
                       CpTh, Dm, (const unsigned short*)nullptr, 0,
                       (float*)nullptr, W3h, (const float*)nullptr, (const float*)nullptr,
                       8, Sn, Dm, 1.f, 2, WW, SW, SW);

    // x (B,C,HW) -> seq (B,HW,C)
    hipLaunchKernelGGL(transpose_bll, dim3(32, 32, Bn), dim3(32, 32), 0, stream, x, seq);

    // Matrix powers of A_bar for all layers: I, A^1, then log-doubling
    hipLaunchKernelGGL(pow_init, dim3(DEPTH, Sn), dim3(Sn), 0, stream, Am, Pow);
    for (int m = 1; m < Qc; m <<= 1) {
        hipLaunchKernelGGL(pow_mul, dim3(4, 2, DEPTH * m), dim3(16, 16), 0, stream,
                           Pow, m, m);
    }

    for (int i = 0; i < DEPTH; i++) {
        const unsigned short* Wi_i  = Wih  + (size_t)i * WW;
        const unsigned short* Wo2_i = Wo2h + (size_t)i * WW;
        const unsigned short* M2_i  = M2h  + (size_t)i * SW;
        const unsigned short* W3_i  = W3h  + (size_t)i * SW;
        const float* PowL = Pow + (size_t)i * NPOW * (Sn * Sn);

        hipLaunchKernelGGL(ln_kernel, dim3(Mrows), dim3(256), 0, stream,
                           seq, nbuf, gamma + i * Dm, beta + i * Dm);
        // fused u+ub: [u | ub] = n @ [Wi | M2]^T ; N=1152, grid 9*64 flat
        hipLaunchKernelGGL(gemm_bk64, dim3(9 * 64, 1), dim3(512), 0, stream,
                           nbuf, Dm, (const unsigned short*)nullptr, 0, 0,
                           Wi_i, Dm, M2_i, Dm,
                           ub, u, bi + i * Dm, c2dt + i * Sn,
                           64, Dm + Sn, Dm, 1.f, 0, 0, 0, 0);
        // chunked scan
        hipLaunchKernelGGL(local_scan, dim3(Bn * NCHUNK), dim3(Sn), 0, stream,
                           ub, hs, PowL + (size_t)1 * Sn * Sn);
        hipLaunchKernelGGL(carry_scan, dim3(Bn), dim3(Sn), 0, stream,
                           hs, PowL + (size_t)Qc * Sn * Sn, carry);
        hipLaunchKernelGGL(fixup_scan, dim3(Qc, NCHUNK / 4), dim3(256), 0, stream,
                           hs, hs_bf, PowL, carry);
        // fused output: seq += [hs | u] @ [W3 | Wo*Dp]^T + bo ; K=1152
        hipLaunchKernelGGL(gemm_bk64, dim3(8 * 64, 1), dim3(512), 0, stream,
                           hs_bf, Sn, u, Dm, Sn,
                           W3_i, Sn, Wo2_i, Dm,
                           seq, (unsigned short*)nullptr, bo + i * Dm, (const float*)nullptr,
                           64, Dm, Dm + Sn, 1.f, 1, 0, 0, 0);
    }

    // seq (B,HW,C) -> out (B,C,HW)
    hipLaunchKernelGGL(transpose_bll, dim3(32, 32, Bn), dim3(32, 32), 0, stream, seq, out);
}